// Round 8
// baseline (497.423 us; speedup 1.0000x reference)
//
#include <hip/hip_runtime.h>
#include <hip/hip_bf16.h>

#define EPSV 1e-5f
#define SLOPEV 0.1f
#define AS1 __attribute__((address_space(1)))
#define AS3 __attribute__((address_space(3)))

typedef __attribute__((ext_vector_type(8))) _Float16 h8;  // 8 fp16 (4 VGPR) MFMA frag
typedef __attribute__((ext_vector_type(4))) float f32x4;  // MFMA acc
typedef unsigned int uint32;
typedef unsigned short ushort_t;

// ---- ws layout (bytes) ----
// A planes (fp16 split-2): plane0=H, plane1=M(x2048). Row = 1280ch x 2B = 2560B.
#define PLANE       ((size_t)18063360)
#define WSPLIT_OFF  ((size_t)36126720)    // 2 planes
// wsplit: [cc40][nt16][tap9][prec2][nj4][kq4][ln16][16B] = 47.2 MB
#define PRE_OFF     ((size_t)124968960)   // pre: 16x1024x361 f32
// pred head tensor (16x20x30x361 f32 = 13.87 MB) reuses the wsplit region after k_conv2

// conv2 LDS (bytes) -- R17: 32-col blocks, A (both prec) single-buffered + B dbuf
#define APREC  28224                 // per-prec A: 441 rows x 64B
#define BB     56448                 // 2*APREC (A region)
#define BBUF   12288                 // per B dbuf: 3 taps x 2 prec x 2 nj x 64 lanes x 16B
#define SMEMSZ 81024                 // BB + 2*BBUF -> 2 blocks/CU (2x81.4KB <= 160KiB)

// fp16 2-way split of 8 f32 -> 2 x 4 packed uint32 (fp16 pairs). M term scaled x2048.
__device__ __forceinline__ void split2_pack(const float* f, uint32* ph, uint32* pm) {
#pragma unroll
  for (int i = 0; i < 4; ++i) {
    float a = f[2 * i], b = f[2 * i + 1];
    _Float16 ha = (_Float16)a, hb = (_Float16)b;          // round-to-nearest
    float ra = (a - (float)ha) * 2048.f;                  // exact residual, rescaled
    float rb = (b - (float)hb) * 2048.f;
    _Float16 ma = (_Float16)ra, mb = (_Float16)rb;
    ph[i] = (uint32)__builtin_bit_cast(ushort_t, ha) | ((uint32)__builtin_bit_cast(ushort_t, hb) << 16);
    pm[i] = (uint32)__builtin_bit_cast(ushort_t, ma) | ((uint32)__builtin_bit_cast(ushort_t, mb) << 16);
  }
}

// ---------- kernel 0: conv1 1x1 (512->64) + BN + leaky -> split planes (R16, unchanged) ----------
__global__ __launch_bounds__(256) void k_conv1(
    const float* __restrict__ feat1, const float* __restrict__ w1,
    const float* __restrict__ g1, const float* __restrict__ b1,
    const float* __restrict__ m1, const float* __restrict__ v1,
    char* __restrict__ nbase)
{
  __shared__ __attribute__((aligned(16))) float S[16384];  // w1 [32co][512ci]
  const int bid = blockIdx.x;
  const int bx = bid % 12, cqq = (bid / 12) & 1, b = bid / 24;
  const int t = threadIdx.x;

#pragma unroll
  for (int i = 0; i < 16; ++i) {
    int f4 = t + i * 256;              // [0,4096)
    int j = f4 >> 7, c4 = (f4 & 127) * 4;
    *(float4*)&S[j * 512 + c4] = *(const float4*)&w1[(cqq * 32 + j) * 512 + c4];
  }
  __syncthreads();

  const int cq16 = t >> 7;             // which 16-co half of the staged 32
  const int cq = cqq * 2 + cq16;       // global 16-co group 0..3
  const int p = bx * 128 + (t & 127);
  const int pp = p < 1444 ? p : 1443;
  const float* xp = feat1 + (size_t)(b * 512) * 1444 + pp;
  float acc[16];
#pragma unroll
  for (int j = 0; j < 16; ++j) acc[j] = 0.f;
#pragma unroll 2
  for (int c4 = 0; c4 < 512; c4 += 4) {
    float x0 = xp[(size_t)(c4 + 0) * 1444];
    float x1 = xp[(size_t)(c4 + 1) * 1444];
    float x2 = xp[(size_t)(c4 + 2) * 1444];
    float x3 = xp[(size_t)(c4 + 3) * 1444];
#pragma unroll
    for (int j = 0; j < 16; ++j) {
      float4 w = *(const float4*)&S[(cq16 * 16 + j) * 512 + c4];  // wave-broadcast
      acc[j] = fmaf(x0, w.x, acc[j]);
      acc[j] = fmaf(x1, w.y, acc[j]);
      acc[j] = fmaf(x2, w.z, acc[j]);
      acc[j] = fmaf(x3, w.w, acc[j]);
    }
  }
  if (p >= 1444) return;
  // BN + leaky
#pragma unroll
  for (int j = 0; j < 16; ++j) {
    int co = cq * 16 + j;
    float sc = g1[co] / sqrtf(v1[co] + EPSV);
    float sh = b1[co] - m1[co] * sc;
    float v = fmaf(acc[j], sc, sh);
    acc[j] = v > 0.f ? v : SLOPEV * v;
  }
  int y = p / 38, x = p - (p / 38) * 38;
  int q = ((y & 1) << 1) | (x & 1);
  int s = (1 + (y >> 1)) * 21 + 1 + (x >> 1);
  const int sw = (s >> 1) & 3;
  size_t rowb = ((size_t)(b * 441 + s)) * 2560;
  int grp = (q * 64 + cq * 16) >> 5;     // 64B block index in row
  char* d0 = nbase + rowb + grp * 64;
#pragma unroll
  for (int u = 0; u < 2; ++u) {
    int q4 = ((cq & 1) << 1) | u;
    uint32 H[4], M[4];
    split2_pack(&acc[u * 8], H, M);
    int off = (q4 ^ sw) << 4;
    *(uint4*)(d0 + off)         = make_uint4(H[0], H[1], H[2], H[3]);
    *(uint4*)(d0 + PLANE + off) = make_uint4(M[0], M[1], M[2], M[3]);
  }
}

// ---------- kernel 1: prep rest (borders / wsplit / feat0 repack) (R16, unchanged) ----------
__global__ __launch_bounds__(256) void k_prep(
    const float* __restrict__ feat0, const float* __restrict__ w2,
    char* __restrict__ nbase, char* __restrict__ wsp)
{
  __shared__ __attribute__((aligned(16))) float S[8192];  // union of sections
  const int bid = blockIdx.x;
  const int t = threadIdx.x;

  if (bid < 1600) {
    // ---- zero borders (2 planes) ----
    int gid = bid * 256 + t;             // < 409600 = 160*80*32
    int c16 = gid % 160;
    int r = gid / 160;
    int bp = r % 80;
    int pi = r / 80;                     // [0,32): plane*16 + img
    int s;
    if (bp < 21) s = bp;
    else if (bp < 42) s = 399 + bp;
    else if (bp < 61) s = (bp - 41) * 21;
    else s = (bp - 60) * 21 + 20;
    int plane = pi >> 4, img = pi & 15;
    *(uint4*)(nbase + (size_t)plane * PLANE + ((size_t)(img * 441 + s)) * 2560 + c16 * 16)
        = make_uint4(0u, 0u, 0u, 0u);

  } else if (bid < 4160) {
    // ---- wsplit: w2*32 -> [cc40][nt16][tap9][prec2][nj4][kq4][ln16][16B] ----
    const int blk = bid - 1600;
    const int cc = blk >> 6, nt = (blk >> 2) & 15, nj = blk & 3;
    const float* src = w2 + ((size_t)(nt * 64 + nj * 16) * 1280 + cc * 32) * 9;
#pragma unroll
    for (int i = 0; i < 18; ++i) {
      int idx = t + i * 256;
      int col = idx / 288, d = idx - col * 288;
      S[col * 289 + d] = src[(size_t)col * 11520 + d];
    }
    __syncthreads();
#pragma unroll
    for (int it = 0; it < 3; ++it) {
      int u = t + it * 256;
      if (u < 576) {
        int tap = u / 64, kq = (u >> 4) & 3, ln = u & 15;
        float f[8];
#pragma unroll
        for (int c8 = 0; c8 < 8; ++c8) f[c8] = S[ln * 289 + (kq * 8 + c8) * 9 + tap] * 32.f;
        uint32 H[4], M[4];
        split2_pack(f, H, M);
        size_t ob = ((size_t)(cc * 16 + nt) * 9 + tap) * 8192 + nj * 1024
                  + (kq * 16 + ln) * 16;
        *(uint4*)(wsp + ob)        = make_uint4(H[0], H[1], H[2], H[3]);
        *(uint4*)(wsp + ob + 4096) = make_uint4(M[0], M[1], M[2], M[3]);
      }
    }

  } else {
    // ---- repack feat0 (ch 256-1279) -> swizzled split planes ----
    const int bid4 = bid - 4160;
    const int px = bid4 % 6, cy = (bid4 / 6) % 16, b = bid4 / 96;
    const int p0 = px * 64, c0 = 256 + cy * 64;
#pragma unroll
    for (int j = 0; j < 16; ++j) {
      int c_l = (t >> 6) + j * 4;
      int p_l = t & 63;
      float v = 0.f;
      int pos = p0 + p_l;
      if (pos < 361)
        v = feat0[((size_t)(b * 1024 + (c0 - 256) + c_l)) * 361 + pos];
      S[c_l * 65 + p_l] = v;
    }
    __syncthreads();
#pragma unroll
    for (int jj = 0; jj < 2; ++jj) {
      int p_l = (t >> 3) + jj * 32;
      int cgrp = t & 7;
      int pos = p0 + p_l;
      if (pos < 361) {
        int y = pos / 19, x = pos - (pos / 19) * 19;
        int s = (y + 1) * 21 + x + 1;
        float f[8];
#pragma unroll
        for (int u = 0; u < 8; ++u) f[u] = S[(cgrp * 8 + u) * 65 + p_l];
        uint32 H[4], M[4];
        split2_pack(f, H, M);
        int ch8 = c0 + cgrp * 8;
        int grp = ch8 >> 5, q4 = (ch8 >> 3) & 3;
        size_t byteo = ((size_t)(b * 441 + s)) * 2560 + grp * 64
                     + ((q4 ^ ((s >> 1) & 3)) << 4);
        *(uint4*)(nbase + byteo)         = make_uint4(H[0], H[1], H[2], H[3]);
        *(uint4*)(nbase + PLANE + byteo) = make_uint4(M[0], M[1], M[2], M[3]);
      }
    }
  }
}

// ---------- kernel 2: conv2 3x3 (1280->1024), 3-term split-fp16 16x16x32 MFMA ----------
// R17 = R14's verified 32-col 2-blocks/CU body with its two poisons removed:
//  (1) __launch_bounds__(512, 2): R14's (512,4) made the allocator squeeze to 64 VGPR
//      and spill 56MB to scratch. At (512,2) the allocator picks ~90-115 (<=128), so
//      LDS (81KB) still gives 2 blocks/CU with 4 waves/EU and zero spill.
//  (2) XCD mapping: n2=bid>>4, imgcode=bid&15, img=((imgcode&7)<<1)|(imgcode>>3):
//      each XCD holds imgs {2x,2x+1} x all 32 col-tiles -> per-iter L2 footprint
//      ~113KB A + ~1.2MB B < 4MB (R14's img=bid>>5 spread imgs across all XCDs).
// Sibling block on each CU covers the A-stage drain + phase barrier stalls that cap
// the 1-block/CU schedule at ~62% MfmaUtil.
__global__ __launch_bounds__(512, 2) void k_conv2(
    const char* __restrict__ nbase, const char* __restrict__ wsp,
    const float* __restrict__ g2, const float* __restrict__ b2,
    const float* __restrict__ m2, const float* __restrict__ v2,
    float* __restrict__ pre)
{
  __shared__ __attribute__((aligned(16))) unsigned char smem[SMEMSZ];

  const int bid = blockIdx.x;
  const int n2 = bid >> 4;                                  // 32-col output tile 0..31
  const int imgcode = bid & 15;
  const int img = ((imgcode & 7) << 1) | (imgcode >> 3);    // XCD-local img pairs
  const int co0 = n2 * 32;
  const int njb = (n2 & 1) * 2;         // nj slice within the 64-col wsplit group

  const int tid = threadIdx.x;
  const int wv = tid >> 6;
  const int lane = tid & 63;
  const int ln = lane & 15;
  const int q = lane >> 4;

  int arow[3];
#pragma unroll
  for (int mi = 0; mi < 3; ++mi) {
    int p = wv * 48 + mi * 16 + ln;
    p = p > 360 ? 360 : p;
    arow[mi] = (p / 19) * 21 + (p - (p / 19) * 19);
  }

  f32x4 acc0[3][2], acc1[3][2];
#pragma unroll
  for (int mi = 0; mi < 3; ++mi)
#pragma unroll
    for (int nj = 0; nj < 2; ++nj) { acc0[mi][nj] = (f32x4)0.f; acc1[mi][nj] = (f32x4)0.f; }

  const size_t imgbase = (size_t)(img * 441) * 2560;
  const size_t wnt = (size_t)(n2 >> 1) * 9 * 8192;

  // prologue: issue B phase 0 into buf0 (768 x 16B)
  {
    const char* bs = wsp + wnt;
#pragma unroll
    for (int i = 0; i < 2; ++i) {
      int idx = tid + i * 512;
      if (idx < 768) {
        int t3s = idx >> 8, r = idx & 255;
        int prec = r >> 7, njx = (r >> 6) & 1, w = r & 63;
        __builtin_amdgcn_global_load_lds(
            (const AS1 uint32*)(bs + t3s * 8192 + prec * 4096 + (njb + njx) * 1024 + w * 16),
            (AS3 uint32*)(smem + BB + idx * 16), 16, 0, 0);
      }
    }
  }

#pragma unroll 1
  for (int cc = 0; cc < 1280; cc += 32) {
    // ---- A(cc) both-plane DMA (3528 x 16B); prev-iter reads done at its last barrier ----
#pragma unroll
    for (int i = 0; i < 7; ++i) {
      int idx = tid + i * 512;
      if (idx < 3528) {
        int pr = idx / 1764;
        int r  = idx - pr * 1764;
        const char* src = nbase + (size_t)pr * PLANE + imgbase
                        + (size_t)(r >> 2) * 2560 + (cc << 1) + ((r & 3) << 4);
        __builtin_amdgcn_global_load_lds((const AS1 uint32*)src,
            (AS3 uint32*)(smem + idx * 16), 16, 0, 0);
      }
    }
    __syncthreads();   // A(cc) + B(phase 0) LDS ready (sibling block hides this drain)

#pragma unroll
    for (int p = 0; p < 3; ++p) {
      const int P = (cc >> 5) * 3 + p;
      if (P + 1 < 120) {
        const int nc = (P + 1) / 3, ntb = ((P + 1) - nc * 3) * 3;
        const char* bs = wsp + ((size_t)nc * 144 + (size_t)ntb) * 8192 + wnt;
        char* bd = (char*)smem + BB + ((P + 1) & 1) * BBUF;
#pragma unroll
        for (int i = 0; i < 2; ++i) {
          int idx = tid + i * 512;
          if (idx < 768) {
            int t3s = idx >> 8, r = idx & 255;
            int prec = r >> 7, njx = (r >> 6) & 1, w = r & 63;
            __builtin_amdgcn_global_load_lds(
                (const AS1 uint32*)(bs + t3s * 8192 + prec * 4096 + (njb + njx) * 1024 + w * 16),
                (AS3 uint32*)(bd + idx * 16), 16, 0, 0);
          }
        }
      }

      const unsigned char* bufR = smem + BB + (P & 1) * BBUF;
      __builtin_amdgcn_s_setprio(1);
#pragma unroll
      for (int t3 = 0; t3 < 3; ++t3) {
        const int trow = p * 21 + t3;
        h8 A0[3], A1[3];
#pragma unroll
        for (int mi = 0; mi < 3; ++mi) {
          int srow = arow[mi] + trow;
          int aoff = srow * 64 + ((q ^ ((srow >> 1) & 3)) << 4);
          A0[mi] = *(const h8*)(smem + aoff);           // H from LDS
          A1[mi] = *(const h8*)(smem + APREC + aoff);   // M from LDS
        }
#pragma unroll
        for (int nj = 0; nj < 2; ++nj) {
          const unsigned char* bp0 = bufR + t3 * 4096 + nj * 1024 + lane * 16;
          h8 B0 = *(const h8*)(bp0);
          h8 B1 = *(const h8*)(bp0 + 2048);
#pragma unroll
          for (int mi = 0; mi < 3; ++mi) {
            acc0[mi][nj] = __builtin_amdgcn_mfma_f32_16x16x32_f16(A0[mi], B0, acc0[mi][nj], 0, 0, 0);
            acc1[mi][nj] = __builtin_amdgcn_mfma_f32_16x16x32_f16(A0[mi], B1, acc1[mi][nj], 0, 0, 0);
            acc1[mi][nj] = __builtin_amdgcn_mfma_f32_16x16x32_f16(A1[mi], B0, acc1[mi][nj], 0, 0, 0);
          }
        }
      }
      __builtin_amdgcn_s_setprio(0);
      __syncthreads();
    }
  }

  // ---- epilogue: combine split terms + BN + leaky, direct stores ----
#pragma unroll
  for (int nj = 0; nj < 2; ++nj) {
    int co = co0 + nj * 16 + ln;
    float sc = g2[co] / sqrtf(v2[co] + EPSV) * 0.03125f;   // fold /32 weight scale
    float sh = b2[co] - m2[co] * (sc * 32.f);
    float* op = pre + ((size_t)(img * 1024 + co)) * 361;
#pragma unroll
    for (int mi = 0; mi < 3; ++mi) {
#pragma unroll
      for (int r = 0; r < 4; ++r) {
        int p = wv * 48 + mi * 16 + q * 4 + r;
        if (p < 361) {
          float t = fmaf(acc1[mi][nj][r], 4.8828125e-4f, acc0[mi][nj][r]);  // + acc1/2048
          float v = fmaf(t, sc, sh);
          v = v > 0.f ? v : SLOPEV * v;
          op[p] = v;
        }
      }
    }
  }
}

// ---------- kernel 3a: materialize pred[b,k,o,p] = sum_{c==k mod 20} wd[o,c]*pre[b,c,p] + bd[o] ----------
__global__ __launch_bounds__(384) void k_pred(
    const float* __restrict__ pre, const float* __restrict__ wd,
    const float* __restrict__ bd, float* __restrict__ pred)
{
  __shared__ float W[30 * 52];
  const int k = blockIdx.x;          // 0..19
  const int b = blockIdx.y;          // 0..15
  const int t = threadIdx.x;         // 0..383
  const int nj = (1023 - k) / 20 + 1;   // 52 for k<4, else 51

  for (int u = t; u < 30 * 52; u += 384) {
    int o = u / 52, j = u - o * 52;
    W[u] = (j < nj) ? wd[o * 1024 + k + 20 * j] : 0.f;
  }
  __syncthreads();
  if (t >= 361) return;

  const float* xb = pre + (size_t)b * 1024 * 361 + t;
  float acc[30];
#pragma unroll
  for (int o = 0; o < 30; ++o) acc[o] = 0.f;
  for (int j = 0; j < nj; ++j) {
    float x = xb[(size_t)(k + 20 * j) * 361];
#pragma unroll
    for (int o = 0; o < 30; ++o) acc[o] = fmaf(W[o * 52 + j], x, acc[o]);
  }
  float* ob = pred + ((size_t)(b * 20 + k) * 30) * 361 + t;
#pragma unroll
  for (int o = 0; o < 30; ++o) ob[(size_t)o * 361] = acc[o] + bd[o];
}

// ---------- kernel 3b: argmax over k of cls + gather 5 box terms, write final ----------
__global__ __launch_bounds__(64) void k_sel(
    const float* __restrict__ pred, float* __restrict__ out)
{
  const int ph = blockIdx.x, a = blockIdx.y, b = blockIdx.z;
  const int p = ph * 64 + threadIdx.x;
  const bool act = p < 361;
  const int pp = act ? p : 360;
  const float* pb = pred + (size_t)b * 20 * 30 * 361 + pp;

  float best = -3.4e38f; int bidx = 0;
  float cls[20];
#pragma unroll
  for (int kk = 0; kk < 20; ++kk) {
    float s = pb[(size_t)(kk * 30 + a * 6 + 5) * 361];
    cls[kk] = s;
    if (s > best) { best = s; bidx = kk; }   // strict > keeps first index (np tie-break)
  }
  if (!act) return;
#pragma unroll
  for (int kk = 0; kk < 20; ++kk)
    out[((size_t)(b * 125 + a * 25 + 5 + kk)) * 361 + p] = cls[kk];
#pragma unroll
  for (int j = 0; j < 5; ++j)
    out[((size_t)(b * 125 + a * 25 + j)) * 361 + p]
        = pb[(size_t)(bidx * 30 + a * 6 + j) * 361];
}

extern "C" void kernel_launch(void* const* d_in, const int* in_sizes, int n_in,
                              void* d_out, int out_size, void* d_ws, size_t ws_size,
                              hipStream_t stream)
{
  const float* feat0 = (const float*)d_in[0];
  const float* feat1 = (const float*)d_in[1];
  const float* w1    = (const float*)d_in[2];
  const float* g1    = (const float*)d_in[3];
  const float* b1    = (const float*)d_in[4];
  const float* m1    = (const float*)d_in[5];
  const float* v1    = (const float*)d_in[6];
  const float* w2    = (const float*)d_in[7];
  const float* g2    = (const float*)d_in[8];
  const float* b2    = (const float*)d_in[9];
  const float* m2    = (const float*)d_in[10];
  const float* v2    = (const float*)d_in[11];
  const float* wd    = (const float*)d_in[12];
  const float* bd    = (const float*)d_in[13];
  float* out = (float*)d_out;

  char*  nbase = (char*)d_ws;
  char*  wsp   = (char*)d_ws + WSPLIT_OFF;
  float* pre   = (float*)((char*)d_ws + PRE_OFF);
  float* pred  = (float*)((char*)d_ws + WSPLIT_OFF);   // reuse wsplit region (dead after k_conv2)

  k_conv1<<<dim3(384), 256, 0, stream>>>(feat1, w1, g1, b1, m1, v1, nbase);
  k_prep<<<dim3(5696), 256, 0, stream>>>(feat0, w2, nbase, wsp);
  k_conv2<<<dim3(512), 512, 0, stream>>>(nbase, wsp, g2, b2, m2, v2, pre);
  k_pred<<<dim3(20, 16), 384, 0, stream>>>(pre, wd, bd, pred);
  k_sel<<<dim3(6, 5, 16), 64, 0, stream>>>(pred, out);
}

// Round 9
// 407.334 us; speedup vs baseline: 1.2212x; 1.2212x over previous
//
#include <hip/hip_runtime.h>
#include <hip/hip_bf16.h>

#define EPSV 1e-5f
#define SLOPEV 0.1f
#define AS1 __attribute__((address_space(1)))
#define AS3 __attribute__((address_space(3)))

typedef __attribute__((ext_vector_type(8))) _Float16 h8;  // 8 fp16 (4 VGPR) MFMA frag
typedef __attribute__((ext_vector_type(4))) float f32x4;  // MFMA acc
typedef unsigned int uint32;
typedef unsigned short ushort_t;

// ---- ws layout (bytes) ----
// A planes (fp16 split-2): plane0=H, plane1=M(x2048). Row = 1280ch x 2B = 2560B.
#define PLANE       ((size_t)18063360)
#define WSPLIT_OFF  ((size_t)36126720)    // 2 planes
// wsplit: [cc40][nt16][tap9][prec2][nj4][kq4][ln16][16B] = 47.2 MB
#define PRE_OFF     ((size_t)124968960)   // pre: 16x1024x361 f32
// pred head tensor (16x20x30x361 f32 = 13.87 MB) reuses the wsplit region after k_conv2

// conv2 LDS (bytes) -- R15/R16: BOTH A planes double-buffered in LDS + B dbuf
#define APREC  28224                 // per-prec A: 441 rows x 64B
#define ABUF   56448                 // one A buffer (2 prec)
#define BOFF   112896                // 2*ABUF
#define BBUF   24576                 // per B dbuf: 3 taps x 2 prec x 4 nj x 64 lanes x 16B
#define SMEMSZ 162048                // 2*ABUF + 2*BBUF  (<= 163840)

// fp16 2-way split of 8 f32 -> 2 x 4 packed uint32 (fp16 pairs). M term scaled x2048.
__device__ __forceinline__ void split2_pack(const float* f, uint32* ph, uint32* pm) {
#pragma unroll
  for (int i = 0; i < 4; ++i) {
    float a = f[2 * i], b = f[2 * i + 1];
    _Float16 ha = (_Float16)a, hb = (_Float16)b;          // round-to-nearest
    float ra = (a - (float)ha) * 2048.f;                  // exact residual, rescaled
    float rb = (b - (float)hb) * 2048.f;
    _Float16 ma = (_Float16)ra, mb = (_Float16)rb;
    ph[i] = (uint32)__builtin_bit_cast(ushort_t, ha) | ((uint32)__builtin_bit_cast(ushort_t, hb) << 16);
    pm[i] = (uint32)__builtin_bit_cast(ushort_t, ma) | ((uint32)__builtin_bit_cast(ushort_t, mb) << 16);
  }
}

// conv1 output store: reorg swizzle + split planes (identical math to R16)
__device__ __forceinline__ void conv1_store(char* __restrict__ nbase, const float* acc,
                                            int b, int p, int cq) {
  int y = p / 38, x = p - (p / 38) * 38;
  int q = ((y & 1) << 1) | (x & 1);
  int s = (1 + (y >> 1)) * 21 + 1 + (x >> 1);
  const int sw = (s >> 1) & 3;
  size_t rowb = ((size_t)(b * 441 + s)) * 2560;
  int grp = (q * 64 + cq * 16) >> 5;     // 64B block index in row
  char* d0 = nbase + rowb + grp * 64;
#pragma unroll
  for (int u = 0; u < 2; ++u) {
    int q4 = ((cq & 1) << 1) | u;
    uint32 H[4], M[4];
    split2_pack(&acc[u * 8], H, M);
    int off = (q4 ^ sw) << 4;
    *(uint4*)(d0 + off)         = make_uint4(H[0], H[1], H[2], H[3]);
    *(uint4*)(d0 + PLANE + off) = make_uint4(M[0], M[1], M[2], M[3]);
  }
}

// ---------- kernel 1: fused prep (R18: conv1 2px/thread merged back with streaming) ----------
// blocks [0,192):      conv1 1x1 (512->64), 2 px/thread (FMA-bound, was LDS-issue-bound)
// blocks [192,1792):   zero padded borders of the 2 A planes
// blocks [1792,4352):  wsplit (w2*32 -> frag-ordered fp16 split planes)
// blocks [4352,5888):  repack feat0 (ch 256-1279) -> swizzled split planes
// conv1 (compute-bound, dispatched first) overlaps the memory-bound sections.
__global__ __launch_bounds__(256) void k_prep(
    const float* __restrict__ feat1, const float* __restrict__ w1,
    const float* __restrict__ g1, const float* __restrict__ b1,
    const float* __restrict__ m1, const float* __restrict__ v1,
    const float* __restrict__ feat0, const float* __restrict__ w2,
    char* __restrict__ nbase, char* __restrict__ wsp)
{
  __shared__ __attribute__((aligned(16))) float S[16384];  // 64KB union of all sections
  const int bid = blockIdx.x;
  const int t = threadIdx.x;

  if (bid < 192) {
    // ---- conv1: 16 img x 2 co-groups(32) x 6 px-chunks(256) ----
    const int bx = bid % 6, cqq = (bid / 6) & 1, b = bid / 12;
    // stage w1 [32co][512ci] (64 KB), coalesced float4
#pragma unroll
    for (int i = 0; i < 16; ++i) {
      int f4 = t + i * 256;              // [0,4096)
      int j = f4 >> 7, c4 = (f4 & 127) * 4;
      *(float4*)&S[j * 512 + c4] = *(const float4*)&w1[(cqq * 32 + j) * 512 + c4];
    }
    __syncthreads();
    const int t2 = t & 127;
    const int cq16 = t >> 7;             // which 16-co half of the staged 32
    const int cq = cqq * 2 + cq16;       // global 16-co group 0..3
    const int pA = bx * 256 + t2;        // always < 1408 < 1444 (valid)
    const int pB = pA + 128;             // may exceed 1443 (guarded)
    const int ppB = pB < 1444 ? pB : 1443;
    const float* xpA = feat1 + (size_t)(b * 512) * 1444 + pA;
    const float* xpB = feat1 + (size_t)(b * 512) * 1444 + ppB;
    float accA[16], accB[16];
#pragma unroll
    for (int j = 0; j < 16; ++j) { accA[j] = 0.f; accB[j] = 0.f; }
#pragma unroll 2
    for (int c4 = 0; c4 < 512; c4 += 4) {
      float a0 = xpA[(size_t)(c4 + 0) * 1444];
      float a1 = xpA[(size_t)(c4 + 1) * 1444];
      float a2 = xpA[(size_t)(c4 + 2) * 1444];
      float a3 = xpA[(size_t)(c4 + 3) * 1444];
      float e0 = xpB[(size_t)(c4 + 0) * 1444];
      float e1 = xpB[(size_t)(c4 + 1) * 1444];
      float e2 = xpB[(size_t)(c4 + 2) * 1444];
      float e3 = xpB[(size_t)(c4 + 3) * 1444];
#pragma unroll
      for (int j = 0; j < 16; ++j) {
        float4 w = *(const float4*)&S[(cq16 * 16 + j) * 512 + c4];  // wave-broadcast
        accA[j] = fmaf(a0, w.x, accA[j]);
        accA[j] = fmaf(a1, w.y, accA[j]);
        accA[j] = fmaf(a2, w.z, accA[j]);
        accA[j] = fmaf(a3, w.w, accA[j]);
        accB[j] = fmaf(e0, w.x, accB[j]);
        accB[j] = fmaf(e1, w.y, accB[j]);
        accB[j] = fmaf(e2, w.z, accB[j]);
        accB[j] = fmaf(e3, w.w, accB[j]);
      }
    }
    // BN + leaky (sc/sh computed once, applied to both px)
#pragma unroll
    for (int j = 0; j < 16; ++j) {
      int co = cq * 16 + j;
      float sc = g1[co] / sqrtf(v1[co] + EPSV);
      float sh = b1[co] - m1[co] * sc;
      float va = fmaf(accA[j], sc, sh);
      accA[j] = va > 0.f ? va : SLOPEV * va;
      float vb = fmaf(accB[j], sc, sh);
      accB[j] = vb > 0.f ? vb : SLOPEV * vb;
    }
    conv1_store(nbase, accA, b, pA, cq);
    if (pB < 1444) conv1_store(nbase, accB, b, pB, cq);

  } else if (bid < 1792) {
    // ---- zero borders (2 planes) ----
    int gid = (bid - 192) * 256 + t;     // < 409600 = 160*80*32
    int c16 = gid % 160;
    int r = gid / 160;
    int bp = r % 80;
    int pi = r / 80;                     // [0,32): plane*16 + img
    int s;
    if (bp < 21) s = bp;
    else if (bp < 42) s = 399 + bp;
    else if (bp < 61) s = (bp - 41) * 21;
    else s = (bp - 60) * 21 + 20;
    int plane = pi >> 4, img = pi & 15;
    *(uint4*)(nbase + (size_t)plane * PLANE + ((size_t)(img * 441 + s)) * 2560 + c16 * 16)
        = make_uint4(0u, 0u, 0u, 0u);

  } else if (bid < 4352) {
    // ---- wsplit: w2*32 -> [cc40][nt16][tap9][prec2][nj4][kq4][ln16][16B] ----
    const int blk = bid - 1792;
    const int cc = blk >> 6, nt = (blk >> 2) & 15, nj = blk & 3;
    const float* src = w2 + ((size_t)(nt * 64 + nj * 16) * 1280 + cc * 32) * 9;
#pragma unroll
    for (int i = 0; i < 18; ++i) {
      int idx = t + i * 256;
      int col = idx / 288, d = idx - col * 288;
      S[col * 289 + d] = src[(size_t)col * 11520 + d];
    }
    __syncthreads();
#pragma unroll
    for (int it = 0; it < 3; ++it) {
      int u = t + it * 256;
      if (u < 576) {
        int tap = u / 64, kq = (u >> 4) & 3, ln = u & 15;
        float f[8];
#pragma unroll
        for (int c8 = 0; c8 < 8; ++c8) f[c8] = S[ln * 289 + (kq * 8 + c8) * 9 + tap] * 32.f;
        uint32 H[4], M[4];
        split2_pack(f, H, M);
        size_t ob = ((size_t)(cc * 16 + nt) * 9 + tap) * 8192 + nj * 1024
                  + (kq * 16 + ln) * 16;
        *(uint4*)(wsp + ob)        = make_uint4(H[0], H[1], H[2], H[3]);
        *(uint4*)(wsp + ob + 4096) = make_uint4(M[0], M[1], M[2], M[3]);
      }
    }

  } else {
    // ---- repack feat0 (ch 256-1279) -> swizzled split planes ----
    const int bid4 = bid - 4352;
    const int px = bid4 % 6, cy = (bid4 / 6) % 16, b = bid4 / 96;
    const int p0 = px * 64, c0 = 256 + cy * 64;
#pragma unroll
    for (int j = 0; j < 16; ++j) {
      int c_l = (t >> 6) + j * 4;
      int p_l = t & 63;
      float v = 0.f;
      int pos = p0 + p_l;
      if (pos < 361)
        v = feat0[((size_t)(b * 1024 + (c0 - 256) + c_l)) * 361 + pos];
      S[c_l * 65 + p_l] = v;
    }
    __syncthreads();
#pragma unroll
    for (int jj = 0; jj < 2; ++jj) {
      int p_l = (t >> 3) + jj * 32;
      int cgrp = t & 7;
      int pos = p0 + p_l;
      if (pos < 361) {
        int y = pos / 19, x = pos - (pos / 19) * 19;
        int s = (y + 1) * 21 + x + 1;
        float f[8];
#pragma unroll
        for (int u = 0; u < 8; ++u) f[u] = S[(cgrp * 8 + u) * 65 + p_l];
        uint32 H[4], M[4];
        split2_pack(f, H, M);
        int ch8 = c0 + cgrp * 8;
        int grp = ch8 >> 5, q4 = (ch8 >> 3) & 3;
        size_t byteo = ((size_t)(b * 441 + s)) * 2560 + grp * 64
                     + ((q4 ^ ((s >> 1) & 3)) << 4);
        *(uint4*)(nbase + byteo)         = make_uint4(H[0], H[1], H[2], H[3]);
        *(uint4*)(nbase + PLANE + byteo) = make_uint4(M[0], M[1], M[2], M[3]);
      }
    }
  }
}

// ---------- kernel 2: conv2 3x3 (1280->1024), 3-term split-fp16 16x16x32 MFMA ----------
// R16 verified version (338us, MfmaUtil 60.6): A double-buffered in LDS, DMAs issued
// in thirds across the 3 phases, 3 barriers/iter, XCD-aware img mapping. R17's 32-col
// 2-blocks/CU attempt failed to pack (occupancy stayed 1 block/CU; 2x81.4KB doesn't
// fit after WG rounding) -- 64-col 1-block/CU is this problem's structural optimum
// for the 2-barrier-class schedule.
__global__ __launch_bounds__(512, 2) void k_conv2(
    const char* __restrict__ nbase, const char* __restrict__ wsp,
    const float* __restrict__ g2, const float* __restrict__ b2,
    const float* __restrict__ m2, const float* __restrict__ v2,
    float* __restrict__ pre)
{
  __shared__ __attribute__((aligned(16))) unsigned char smem[SMEMSZ];

  const int bid = blockIdx.x;
  const int img = (bid & 7) * 2 + ((bid >> 3) & 1);
  const int ntile = (bid >> 4) & 15;
  const int co0 = ntile * 64;

  const int tid = threadIdx.x;
  const int wv = tid >> 6;
  const int lane = tid & 63;
  const int ln = lane & 15;
  const int q = lane >> 4;

  int arow[3];
#pragma unroll
  for (int mi = 0; mi < 3; ++mi) {
    int p = wv * 48 + mi * 16 + ln;
    p = p > 360 ? 360 : p;
    arow[mi] = (p / 19) * 21 + (p - (p / 19) * 19);
  }

  f32x4 acc0[3][4], acc1[3][4];
#pragma unroll
  for (int mi = 0; mi < 3; ++mi)
#pragma unroll
    for (int nj = 0; nj < 4; ++nj) { acc0[mi][nj] = (f32x4)0.f; acc1[mi][nj] = (f32x4)0.f; }

  const size_t imgbase = (size_t)(img * 441) * 2560;
  const size_t wnt = (size_t)ntile * 9 * 8192;

  // prologue: stage A(cc=0) into aBuf0 (3528 x 16B)
#pragma unroll
  for (int i = 0; i < 7; ++i) {
    int idx = tid + i * 512;
    if (idx < 3528) {
      int pr = idx / 1764;
      int r  = idx - pr * 1764;
      const char* src = nbase + (size_t)pr * PLANE + imgbase
                      + (size_t)(r >> 2) * 2560 + ((r & 3) << 4);
      __builtin_amdgcn_global_load_lds((const AS1 uint32*)src,
          (AS3 uint32*)(smem + idx * 16), 16, 0, 0);
    }
  }
  // prologue: B phase 0 into bBuf0 (1536 x 16B = 3/thread)
  {
    const char* bs = wsp + wnt;
#pragma unroll
    for (int i = 0; i < 3; ++i) {
      int idx = tid + i * 512;
      __builtin_amdgcn_global_load_lds((const AS1 uint32*)(bs + idx * 16),
          (AS3 uint32*)(smem + BOFF + idx * 16), 16, 0, 0);
    }
  }
  __syncthreads();   // A(0) + B(0) ready

#pragma unroll 1
  for (int cc = 0; cc < 1280; cc += 32) {
    const int cur = (cc >> 5) & 1;
    const unsigned char* aCur = smem + cur * ABUF;
    char* aNext = (char*)smem + (cur ^ 1) * ABUF;
    const int ccn = cc + 32;
    const bool pn = ccn < 1280;

#pragma unroll
    for (int p = 0; p < 3; ++p) {
      const int P = (cc >> 5) * 3 + p;
      // ---- issue B(P+1) into the other B buffer ----
      if (P + 1 < 120) {
        const int nc = (P + 1) / 3, ntb = ((P + 1) - nc * 3) * 3;
        const char* bs = wsp + ((size_t)nc * 144 + (size_t)ntb) * 8192 + wnt;
        char* bd = (char*)smem + BOFF + ((P + 1) & 1) * BBUF;
#pragma unroll
        for (int i = 0; i < 3; ++i) {
          int idx = tid + i * 512;
          __builtin_amdgcn_global_load_lds((const AS1 uint32*)(bs + idx * 16),
              (AS3 uint32*)(bd + idx * 16), 16, 0, 0);
        }
      }
      // ---- issue this phase's third of A(cc+32) into the idle A buffer ----
      if (pn) {
#pragma unroll
        for (int i = 0; i < 3; ++i) {
          int idx = p * 1176 + i * 512 + tid;
          if (idx < (p + 1) * 1176) {          // 1176 loads per phase (last i: 152 thr)
            int pr = idx / 1764;
            int r  = idx - pr * 1764;
            const char* src = nbase + (size_t)pr * PLANE + imgbase
                            + (size_t)(r >> 2) * 2560 + (ccn << 1) + ((r & 3) << 4);
            __builtin_amdgcn_global_load_lds((const AS1 uint32*)src,
                (AS3 uint32*)(aNext + idx * 16), 16, 0, 0);
          }
        }
      }

      const unsigned char* bufR = smem + BOFF + (P & 1) * BBUF;
      __builtin_amdgcn_s_setprio(1);
#pragma unroll
      for (int t3 = 0; t3 < 3; ++t3) {
        const int trow = p * 21 + t3;
        h8 A0[3], A1[3];
#pragma unroll
        for (int mi = 0; mi < 3; ++mi) {
          int srow = arow[mi] + trow;
          int aoff = srow * 64 + ((q ^ ((srow >> 1) & 3)) << 4);
          A0[mi] = *(const h8*)(aCur + aoff);           // H
          A1[mi] = *(const h8*)(aCur + APREC + aoff);   // M
        }
#pragma unroll
        for (int nj = 0; nj < 4; ++nj) {
          const unsigned char* bp0 = bufR + t3 * 8192 + nj * 1024 + lane * 16;
          h8 B0 = *(const h8*)(bp0);
          h8 B1 = *(const h8*)(bp0 + 4096);
#pragma unroll
          for (int mi = 0; mi < 3; ++mi) {
            acc0[mi][nj] = __builtin_amdgcn_mfma_f32_16x16x32_f16(A0[mi], B0, acc0[mi][nj], 0, 0, 0);
            acc1[mi][nj] = __builtin_amdgcn_mfma_f32_16x16x32_f16(A0[mi], B1, acc1[mi][nj], 0, 0, 0);
            acc1[mi][nj] = __builtin_amdgcn_mfma_f32_16x16x32_f16(A1[mi], B0, acc1[mi][nj], 0, 0, 0);
          }
        }
      }
      __builtin_amdgcn_s_setprio(0);
      __syncthreads();   // drains this phase's DMAs; flips B buffer (and A at p==2)
    }
  }

  // ---- epilogue: combine split terms + BN + leaky, direct stores ----
#pragma unroll
  for (int nj = 0; nj < 4; ++nj) {
    int co = co0 + nj * 16 + ln;
    float sc = g2[co] / sqrtf(v2[co] + EPSV) * 0.03125f;   // fold /32 weight scale
    float sh = b2[co] - m2[co] * (sc * 32.f);
    float* op = pre + ((size_t)(img * 1024 + co)) * 361;
#pragma unroll
    for (int mi = 0; mi < 3; ++mi) {
#pragma unroll
      for (int r = 0; r < 4; ++r) {
        int p = wv * 48 + mi * 16 + q * 4 + r;
        if (p < 361) {
          float t = fmaf(acc1[mi][nj][r], 4.8828125e-4f, acc0[mi][nj][r]);  // + acc1/2048
          float v = fmaf(t, sc, sh);
          v = v > 0.f ? v : SLOPEV * v;
          op[p] = v;
        }
      }
    }
  }
}

// ---------- kernel 3a: materialize pred[b,k,o,p] = sum_{c==k mod 20} wd[o,c]*pre[b,c,p] + bd[o] ----------
__global__ __launch_bounds__(384) void k_pred(
    const float* __restrict__ pre, const float* __restrict__ wd,
    const float* __restrict__ bd, float* __restrict__ pred)
{
  __shared__ float W[30 * 52];
  const int k = blockIdx.x;          // 0..19
  const int b = blockIdx.y;          // 0..15
  const int t = threadIdx.x;         // 0..383
  const int nj = (1023 - k) / 20 + 1;   // 52 for k<4, else 51

  for (int u = t; u < 30 * 52; u += 384) {
    int o = u / 52, j = u - o * 52;
    W[u] = (j < nj) ? wd[o * 1024 + k + 20 * j] : 0.f;
  }
  __syncthreads();
  if (t >= 361) return;

  const float* xb = pre + (size_t)b * 1024 * 361 + t;
  float acc[30];
#pragma unroll
  for (int o = 0; o < 30; ++o) acc[o] = 0.f;
  for (int j = 0; j < nj; ++j) {
    float x = xb[(size_t)(k + 20 * j) * 361];
#pragma unroll
    for (int o = 0; o < 30; ++o) acc[o] = fmaf(W[o * 52 + j], x, acc[o]);
  }
  float* ob = pred + ((size_t)(b * 20 + k) * 30) * 361 + t;
#pragma unroll
  for (int o = 0; o < 30; ++o) ob[(size_t)o * 361] = acc[o] + bd[o];
}

// ---------- kernel 3b: argmax over k of cls + gather 5 box terms, write final ----------
__global__ __launch_bounds__(64) void k_sel(
    const float* __restrict__ pred, float* __restrict__ out)
{
  const int ph = blockIdx.x, a = blockIdx.y, b = blockIdx.z;
  const int p = ph * 64 + threadIdx.x;
  const bool act = p < 361;
  const int pp = act ? p : 360;
  const float* pb = pred + (size_t)b * 20 * 30 * 361 + pp;

  float best = -3.4e38f; int bidx = 0;
  float cls[20];
#pragma unroll
  for (int kk = 0; kk < 20; ++kk) {
    float s = pb[(size_t)(kk * 30 + a * 6 + 5) * 361];
    cls[kk] = s;
    if (s > best) { best = s; bidx = kk; }   // strict > keeps first index (np tie-break)
  }
  if (!act) return;
#pragma unroll
  for (int kk = 0; kk < 20; ++kk)
    out[((size_t)(b * 125 + a * 25 + 5 + kk)) * 361 + p] = cls[kk];
#pragma unroll
  for (int j = 0; j < 5; ++j)
    out[((size_t)(b * 125 + a * 25 + j)) * 361 + p]
        = pb[(size_t)(bidx * 30 + a * 6 + j) * 361];
}

extern "C" void kernel_launch(void* const* d_in, const int* in_sizes, int n_in,
                              void* d_out, int out_size, void* d_ws, size_t ws_size,
                              hipStream_t stream)
{
  const float* feat0 = (const float*)d_in[0];
  const float* feat1 = (const float*)d_in[1];
  const float* w1    = (const float*)d_in[2];
  const float* g1    = (const float*)d_in[3];
  const float* b1    = (const float*)d_in[4];
  const float* m1    = (const float*)d_in[5];
  const float* v1    = (const float*)d_in[6];
  const float* w2    = (const float*)d_in[7];
  const float* g2    = (const float*)d_in[8];
  const float* b2    = (const float*)d_in[9];
  const float* m2    = (const float*)d_in[10];
  const float* v2    = (const float*)d_in[11];
  const float* wd    = (const float*)d_in[12];
  const float* bd    = (const float*)d_in[13];
  float* out = (float*)d_out;

  char*  nbase = (char*)d_ws;
  char*  wsp   = (char*)d_ws + WSPLIT_OFF;
  float* pre   = (float*)((char*)d_ws + PRE_OFF);
  float* pred  = (float*)((char*)d_ws + WSPLIT_OFF);   // reuse wsplit region (dead after k_conv2)

  k_prep<<<dim3(5888), 256, 0, stream>>>(feat1, w1, g1, b1, m1, v1, feat0, w2, nbase, wsp);
  k_conv2<<<dim3(256), 512, 0, stream>>>(nbase, wsp, g2, b2, m2, v2, pre);
  k_pred<<<dim3(20, 16), 384, 0, stream>>>(pre, wd, bd, pred);
  k_sel<<<dim3(6, 5, 16), 64, 0, stream>>>(pred, out);
}

// Round 10
// 407.113 us; speedup vs baseline: 1.2218x; 1.0005x over previous
//
#include <hip/hip_runtime.h>
#include <hip/hip_bf16.h>

#define EPSV 1e-5f
#define SLOPEV 0.1f
#define AS1 __attribute__((address_space(1)))
#define AS3 __attribute__((address_space(3)))

typedef __attribute__((ext_vector_type(8))) _Float16 h8;  // 8 fp16 (4 VGPR) MFMA frag
typedef __attribute__((ext_vector_type(4))) float f32x4;  // MFMA acc
typedef unsigned int uint32;
typedef unsigned short ushort_t;

// ---- ws layout (bytes) ----
// A planes (fp16 split-2): plane0=H, plane1=M(x2048). Row = 1280ch x 2B = 2560B.
#define PLANE       ((size_t)18063360)
#define WSPLIT_OFF  ((size_t)36126720)    // 2 planes
// wsplit: [cc40][nt16][tap9][prec2][nj4][kq4][ln16][16B] = 47.2 MB
#define PRE_OFF     ((size_t)124968960)   // pre: 16x1024x361 f32
// pred head tensor (16x20x30x361 f32 = 13.87 MB) reuses the wsplit region after k_conv2

// conv2 LDS (bytes) -- R15/R16: BOTH A planes double-buffered in LDS + B dbuf
#define APREC  28224                 // per-prec A: 441 rows x 64B
#define ABUF   56448                 // one A buffer (2 prec)
#define BOFF   112896                // 2*ABUF
#define BBUF   24576                 // per B dbuf: 3 taps x 2 prec x 4 nj x 64 lanes x 16B
#define SMEMSZ 162048                // 2*ABUF + 2*BBUF  (<= 163840)

// fp16 2-way split of 8 f32 -> 2 x 4 packed uint32 (fp16 pairs). M term scaled x2048.
__device__ __forceinline__ void split2_pack(const float* f, uint32* ph, uint32* pm) {
#pragma unroll
  for (int i = 0; i < 4; ++i) {
    float a = f[2 * i], b = f[2 * i + 1];
    _Float16 ha = (_Float16)a, hb = (_Float16)b;          // round-to-nearest
    float ra = (a - (float)ha) * 2048.f;                  // exact residual, rescaled
    float rb = (b - (float)hb) * 2048.f;
    _Float16 ma = (_Float16)ra, mb = (_Float16)rb;
    ph[i] = (uint32)__builtin_bit_cast(ushort_t, ha) | ((uint32)__builtin_bit_cast(ushort_t, hb) << 16);
    pm[i] = (uint32)__builtin_bit_cast(ushort_t, ma) | ((uint32)__builtin_bit_cast(ushort_t, mb) << 16);
  }
}

// conv1 output store: reorg swizzle + split planes (identical math to R16)
__device__ __forceinline__ void conv1_store(char* __restrict__ nbase, const float* acc,
                                            int b, int p, int cq) {
  int y = p / 38, x = p - (p / 38) * 38;
  int q = ((y & 1) << 1) | (x & 1);
  int s = (1 + (y >> 1)) * 21 + 1 + (x >> 1);
  const int sw = (s >> 1) & 3;
  size_t rowb = ((size_t)(b * 441 + s)) * 2560;
  int grp = (q * 64 + cq * 16) >> 5;     // 64B block index in row
  char* d0 = nbase + rowb + grp * 64;
#pragma unroll
  for (int u = 0; u < 2; ++u) {
    int q4 = ((cq & 1) << 1) | u;
    uint32 H[4], M[4];
    split2_pack(&acc[u * 8], H, M);
    int off = (q4 ^ sw) << 4;
    *(uint4*)(d0 + off)         = make_uint4(H[0], H[1], H[2], H[3]);
    *(uint4*)(d0 + PLANE + off) = make_uint4(M[0], M[1], M[2], M[3]);
  }
}

// ---------- kernel 1: fused prep (R18: conv1 2px/thread merged with streaming) ----------
__global__ __launch_bounds__(256) void k_prep(
    const float* __restrict__ feat1, const float* __restrict__ w1,
    const float* __restrict__ g1, const float* __restrict__ b1,
    const float* __restrict__ m1, const float* __restrict__ v1,
    const float* __restrict__ feat0, const float* __restrict__ w2,
    char* __restrict__ nbase, char* __restrict__ wsp)
{
  __shared__ __attribute__((aligned(16))) float S[16384];  // 64KB union of all sections
  const int bid = blockIdx.x;
  const int t = threadIdx.x;

  if (bid < 192) {
    // ---- conv1: 16 img x 2 co-groups(32) x 6 px-chunks(256) ----
    const int bx = bid % 6, cqq = (bid / 6) & 1, b = bid / 12;
#pragma unroll
    for (int i = 0; i < 16; ++i) {
      int f4 = t + i * 256;              // [0,4096)
      int j = f4 >> 7, c4 = (f4 & 127) * 4;
      *(float4*)&S[j * 512 + c4] = *(const float4*)&w1[(cqq * 32 + j) * 512 + c4];
    }
    __syncthreads();
    const int t2 = t & 127;
    const int cq16 = t >> 7;             // which 16-co half of the staged 32
    const int cq = cqq * 2 + cq16;       // global 16-co group 0..3
    const int pA = bx * 256 + t2;        // always < 1408 < 1444 (valid)
    const int pB = pA + 128;             // may exceed 1443 (guarded)
    const int ppB = pB < 1444 ? pB : 1443;
    const float* xpA = feat1 + (size_t)(b * 512) * 1444 + pA;
    const float* xpB = feat1 + (size_t)(b * 512) * 1444 + ppB;
    float accA[16], accB[16];
#pragma unroll
    for (int j = 0; j < 16; ++j) { accA[j] = 0.f; accB[j] = 0.f; }
#pragma unroll 2
    for (int c4 = 0; c4 < 512; c4 += 4) {
      float a0 = xpA[(size_t)(c4 + 0) * 1444];
      float a1 = xpA[(size_t)(c4 + 1) * 1444];
      float a2 = xpA[(size_t)(c4 + 2) * 1444];
      float a3 = xpA[(size_t)(c4 + 3) * 1444];
      float e0 = xpB[(size_t)(c4 + 0) * 1444];
      float e1 = xpB[(size_t)(c4 + 1) * 1444];
      float e2 = xpB[(size_t)(c4 + 2) * 1444];
      float e3 = xpB[(size_t)(c4 + 3) * 1444];
#pragma unroll
      for (int j = 0; j < 16; ++j) {
        float4 w = *(const float4*)&S[(cq16 * 16 + j) * 512 + c4];  // wave-broadcast
        accA[j] = fmaf(a0, w.x, accA[j]);
        accA[j] = fmaf(a1, w.y, accA[j]);
        accA[j] = fmaf(a2, w.z, accA[j]);
        accA[j] = fmaf(a3, w.w, accA[j]);
        accB[j] = fmaf(e0, w.x, accB[j]);
        accB[j] = fmaf(e1, w.y, accB[j]);
        accB[j] = fmaf(e2, w.z, accB[j]);
        accB[j] = fmaf(e3, w.w, accB[j]);
      }
    }
    // BN + leaky (sc/sh computed once, applied to both px)
#pragma unroll
    for (int j = 0; j < 16; ++j) {
      int co = cq * 16 + j;
      float sc = g1[co] / sqrtf(v1[co] + EPSV);
      float sh = b1[co] - m1[co] * sc;
      float va = fmaf(accA[j], sc, sh);
      accA[j] = va > 0.f ? va : SLOPEV * va;
      float vb = fmaf(accB[j], sc, sh);
      accB[j] = vb > 0.f ? vb : SLOPEV * vb;
    }
    conv1_store(nbase, accA, b, pA, cq);
    if (pB < 1444) conv1_store(nbase, accB, b, pB, cq);

  } else if (bid < 1792) {
    // ---- zero borders (2 planes) ----
    int gid = (bid - 192) * 256 + t;     // < 409600 = 160*80*32
    int c16 = gid % 160;
    int r = gid / 160;
    int bp = r % 80;
    int pi = r / 80;                     // [0,32): plane*16 + img
    int s;
    if (bp < 21) s = bp;
    else if (bp < 42) s = 399 + bp;
    else if (bp < 61) s = (bp - 41) * 21;
    else s = (bp - 60) * 21 + 20;
    int plane = pi >> 4, img = pi & 15;
    *(uint4*)(nbase + (size_t)plane * PLANE + ((size_t)(img * 441 + s)) * 2560 + c16 * 16)
        = make_uint4(0u, 0u, 0u, 0u);

  } else if (bid < 4352) {
    // ---- wsplit: w2*32 -> [cc40][nt16][tap9][prec2][nj4][kq4][ln16][16B] ----
    const int blk = bid - 1792;
    const int cc = blk >> 6, nt = (blk >> 2) & 15, nj = blk & 3;
    const float* src = w2 + ((size_t)(nt * 64 + nj * 16) * 1280 + cc * 32) * 9;
#pragma unroll
    for (int i = 0; i < 18; ++i) {
      int idx = t + i * 256;
      int col = idx / 288, d = idx - col * 288;
      S[col * 289 + d] = src[(size_t)col * 11520 + d];
    }
    __syncthreads();
#pragma unroll
    for (int it = 0; it < 3; ++it) {
      int u = t + it * 256;
      if (u < 576) {
        int tap = u / 64, kq = (u >> 4) & 3, ln = u & 15;
        float f[8];
#pragma unroll
        for (int c8 = 0; c8 < 8; ++c8) f[c8] = S[ln * 289 + (kq * 8 + c8) * 9 + tap] * 32.f;
        uint32 H[4], M[4];
        split2_pack(f, H, M);
        size_t ob = ((size_t)(cc * 16 + nt) * 9 + tap) * 8192 + nj * 1024
                  + (kq * 16 + ln) * 16;
        *(uint4*)(wsp + ob)        = make_uint4(H[0], H[1], H[2], H[3]);
        *(uint4*)(wsp + ob + 4096) = make_uint4(M[0], M[1], M[2], M[3]);
      }
    }

  } else {
    // ---- repack feat0 (ch 256-1279) -> swizzled split planes ----
    const int bid4 = bid - 4352;
    const int px = bid4 % 6, cy = (bid4 / 6) % 16, b = bid4 / 96;
    const int p0 = px * 64, c0 = 256 + cy * 64;
#pragma unroll
    for (int j = 0; j < 16; ++j) {
      int c_l = (t >> 6) + j * 4;
      int p_l = t & 63;
      float v = 0.f;
      int pos = p0 + p_l;
      if (pos < 361)
        v = feat0[((size_t)(b * 1024 + (c0 - 256) + c_l)) * 361 + pos];
      S[c_l * 65 + p_l] = v;
    }
    __syncthreads();
#pragma unroll
    for (int jj = 0; jj < 2; ++jj) {
      int p_l = (t >> 3) + jj * 32;
      int cgrp = t & 7;
      int pos = p0 + p_l;
      if (pos < 361) {
        int y = pos / 19, x = pos - (pos / 19) * 19;
        int s = (y + 1) * 21 + x + 1;
        float f[8];
#pragma unroll
        for (int u = 0; u < 8; ++u) f[u] = S[(cgrp * 8 + u) * 65 + p_l];
        uint32 H[4], M[4];
        split2_pack(f, H, M);
        int ch8 = c0 + cgrp * 8;
        int grp = ch8 >> 5, q4 = (ch8 >> 3) & 3;
        size_t byteo = ((size_t)(b * 441 + s)) * 2560 + grp * 64
                     + ((q4 ^ ((s >> 1) & 3)) << 4);
        *(uint4*)(nbase + byteo)         = make_uint4(H[0], H[1], H[2], H[3]);
        *(uint4*)(nbase + PLANE + byteo) = make_uint4(M[0], M[1], M[2], M[3]);
      }
    }
  }
}

// ---------- kernel 2: conv2 3x3 (1280->1024), 3-term split-fp16 16x16x32 MFMA ----------
// R19 = R16 skeleton (A dbuf in LDS, 3 barriers/iter, XCD img map) + two lockstep-
// breaking changes (no sync-structure change):
//  (1) wave-staggered t3 order: waves with (wv>>2)&1 visit taps {1,2,0} instead of
//      {0,1,2} -- the two waves sharing a SIMD desync their LDS-read bursts and MFMA
//      clusters (anti-phase), spreading LDS traffic in time. Only changes the fp32
//      accumulation order of tap partials (~1e-6, far under the split error).
//  (2) cross-barrier A-frag prefetch: A(cc) holds all 9 taps, so the next phase's
//      first-t3 A frags (6 x h8 = 24 VGPR) are read BEFORE the phase barrier and
//      consumed right after it -- removes the post-barrier ds_read->MFMA stall.
//      Statically resolved (p unrolled; skipped across the cc-boundary buffer flip).
__global__ __launch_bounds__(512, 2) void k_conv2(
    const char* __restrict__ nbase, const char* __restrict__ wsp,
    const float* __restrict__ g2, const float* __restrict__ b2,
    const float* __restrict__ m2, const float* __restrict__ v2,
    float* __restrict__ pre)
{
  __shared__ __attribute__((aligned(16))) unsigned char smem[SMEMSZ];

  const int bid = blockIdx.x;
  const int img = (bid & 7) * 2 + ((bid >> 3) & 1);
  const int ntile = (bid >> 4) & 15;
  const int co0 = ntile * 64;

  const int tid = threadIdx.x;
  const int wv = tid >> 6;
  const int lane = tid & 63;
  const int ln = lane & 15;
  const int q = lane >> 4;
  const int t3base = (wv >> 2) & 1;     // stagger: waves 4-7 start at tap 1

  int arow[3];
#pragma unroll
  for (int mi = 0; mi < 3; ++mi) {
    int p = wv * 48 + mi * 16 + ln;
    p = p > 360 ? 360 : p;
    arow[mi] = (p / 19) * 21 + (p - (p / 19) * 19);
  }

  f32x4 acc0[3][4], acc1[3][4];
#pragma unroll
  for (int mi = 0; mi < 3; ++mi)
#pragma unroll
    for (int nj = 0; nj < 4; ++nj) { acc0[mi][nj] = (f32x4)0.f; acc1[mi][nj] = (f32x4)0.f; }

  const size_t imgbase = (size_t)(img * 441) * 2560;
  const size_t wnt = (size_t)ntile * 9 * 8192;

  // prologue: stage A(cc=0) into aBuf0 (3528 x 16B)
#pragma unroll
  for (int i = 0; i < 7; ++i) {
    int idx = tid + i * 512;
    if (idx < 3528) {
      int pr = idx / 1764;
      int r  = idx - pr * 1764;
      const char* src = nbase + (size_t)pr * PLANE + imgbase
                      + (size_t)(r >> 2) * 2560 + ((r & 3) << 4);
      __builtin_amdgcn_global_load_lds((const AS1 uint32*)src,
          (AS3 uint32*)(smem + idx * 16), 16, 0, 0);
    }
  }
  // prologue: B phase 0 into bBuf0 (1536 x 16B = 3/thread)
  {
    const char* bs = wsp + wnt;
#pragma unroll
    for (int i = 0; i < 3; ++i) {
      int idx = tid + i * 512;
      __builtin_amdgcn_global_load_lds((const AS1 uint32*)(bs + idx * 16),
          (AS3 uint32*)(smem + BOFF + idx * 16), 16, 0, 0);
    }
  }
  __syncthreads();   // A(0) + B(0) ready

  h8 pf0[3], pf1[3];   // cross-barrier A prefetch registers

#pragma unroll 1
  for (int cc = 0; cc < 1280; cc += 32) {
    const int cur = (cc >> 5) & 1;
    const unsigned char* aCur = smem + cur * ABUF;
    char* aNext = (char*)smem + (cur ^ 1) * ABUF;
    const int ccn = cc + 32;
    const bool pn = ccn < 1280;

#pragma unroll
    for (int p = 0; p < 3; ++p) {
      const int P = (cc >> 5) * 3 + p;
      // ---- issue B(P+1) into the other B buffer ----
      if (P + 1 < 120) {
        const int nc = (P + 1) / 3, ntb = ((P + 1) - nc * 3) * 3;
        const char* bs = wsp + ((size_t)nc * 144 + (size_t)ntb) * 8192 + wnt;
        char* bd = (char*)smem + BOFF + ((P + 1) & 1) * BBUF;
#pragma unroll
        for (int i = 0; i < 3; ++i) {
          int idx = tid + i * 512;
          __builtin_amdgcn_global_load_lds((const AS1 uint32*)(bs + idx * 16),
              (AS3 uint32*)(bd + idx * 16), 16, 0, 0);
        }
      }
      // ---- issue this phase's third of A(cc+32) into the idle A buffer ----
      if (pn) {
#pragma unroll
        for (int i = 0; i < 3; ++i) {
          int idx = p * 1176 + i * 512 + tid;
          if (idx < (p + 1) * 1176) {          // 1176 loads per phase (last i: 152 thr)
            int pr = idx / 1764;
            int r  = idx - pr * 1764;
            const char* src = nbase + (size_t)pr * PLANE + imgbase
                            + (size_t)(r >> 2) * 2560 + (ccn << 1) + ((r & 3) << 4);
            __builtin_amdgcn_global_load_lds((const AS1 uint32*)src,
                (AS3 uint32*)(aNext + idx * 16), 16, 0, 0);
          }
        }
      }

      const unsigned char* bufR = smem + BOFF + (P & 1) * BBUF;
      __builtin_amdgcn_s_setprio(1);
#pragma unroll
      for (int t3i = 0; t3i < 3; ++t3i) {
        int t3 = t3i + t3base; t3 = t3 >= 3 ? t3 - 3 : t3;   // staggered visit order
        const int trow = p * 21 + t3;
        h8 A0[3], A1[3];
        if (t3i == 0 && p > 0) {
          // consume cross-barrier prefetch (written at end of phase p-1)
#pragma unroll
          for (int mi = 0; mi < 3; ++mi) { A0[mi] = pf0[mi]; A1[mi] = pf1[mi]; }
        } else {
#pragma unroll
          for (int mi = 0; mi < 3; ++mi) {
            int srow = arow[mi] + trow;
            int aoff = srow * 64 + ((q ^ ((srow >> 1) & 3)) << 4);
            A0[mi] = *(const h8*)(aCur + aoff);           // H
            A1[mi] = *(const h8*)(aCur + APREC + aoff);   // M
          }
        }
#pragma unroll
        for (int nj = 0; nj < 4; ++nj) {
          const unsigned char* bp0 = bufR + t3 * 8192 + nj * 1024 + lane * 16;
          h8 B0 = *(const h8*)(bp0);
          h8 B1 = *(const h8*)(bp0 + 4096);
#pragma unroll
          for (int mi = 0; mi < 3; ++mi) {
            acc0[mi][nj] = __builtin_amdgcn_mfma_f32_16x16x32_f16(A0[mi], B0, acc0[mi][nj], 0, 0, 0);
            acc1[mi][nj] = __builtin_amdgcn_mfma_f32_16x16x32_f16(A0[mi], B1, acc1[mi][nj], 0, 0, 0);
            acc1[mi][nj] = __builtin_amdgcn_mfma_f32_16x16x32_f16(A1[mi], B0, acc1[mi][nj], 0, 0, 0);
          }
        }
      }
      __builtin_amdgcn_s_setprio(0);
      // ---- prefetch next phase's first-t3 A frags (aCur stable; pre-barrier) ----
      if (p < 2) {
        const int trowN = (p + 1) * 21 + t3base;
#pragma unroll
        for (int mi = 0; mi < 3; ++mi) {
          int srow = arow[mi] + trowN;
          int aoff = srow * 64 + ((q ^ ((srow >> 1) & 3)) << 4);
          pf0[mi] = *(const h8*)(aCur + aoff);
          pf1[mi] = *(const h8*)(aCur + APREC + aoff);
        }
      }
      __syncthreads();   // drains this phase's DMAs; flips B buffer (and A at p==2)
    }
  }

  // ---- epilogue: combine split terms + BN + leaky, direct stores ----
#pragma unroll
  for (int nj = 0; nj < 4; ++nj) {
    int co = co0 + nj * 16 + ln;
    float sc = g2[co] / sqrtf(v2[co] + EPSV) * 0.03125f;   // fold /32 weight scale
    float sh = b2[co] - m2[co] * (sc * 32.f);
    float* op = pre + ((size_t)(img * 1024 + co)) * 361;
#pragma unroll
    for (int mi = 0; mi < 3; ++mi) {
#pragma unroll
      for (int r = 0; r < 4; ++r) {
        int p = wv * 48 + mi * 16 + q * 4 + r;
        if (p < 361) {
          float t = fmaf(acc1[mi][nj][r], 4.8828125e-4f, acc0[mi][nj][r]);  // + acc1/2048
          float v = fmaf(t, sc, sh);
          v = v > 0.f ? v : SLOPEV * v;
          op[p] = v;
        }
      }
    }
  }
}

// ---------- kernel 3a: materialize pred[b,k,o,p] = sum_{c==k mod 20} wd[o,c]*pre[b,c,p] + bd[o] ----------
__global__ __launch_bounds__(384) void k_pred(
    const float* __restrict__ pre, const float* __restrict__ wd,
    const float* __restrict__ bd, float* __restrict__ pred)
{
  __shared__ float W[30 * 52];
  const int k = blockIdx.x;          // 0..19
  const int b = blockIdx.y;          // 0..15
  const int t = threadIdx.x;         // 0..383
  const int nj = (1023 - k) / 20 + 1;   // 52 for k<4, else 51

  for (int u = t; u < 30 * 52; u += 384) {
    int o = u / 52, j = u - o * 52;
    W[u] = (j < nj) ? wd[o * 1024 + k + 20 * j] : 0.f;
  }
  __syncthreads();
  if (t >= 361) return;

  const float* xb = pre + (size_t)b * 1024 * 361 + t;
  float acc[30];
#pragma unroll
  for (int o = 0; o < 30; ++o) acc[o] = 0.f;
  for (int j = 0; j < nj; ++j) {
    float x = xb[(size_t)(k + 20 * j) * 361];
#pragma unroll
    for (int o = 0; o < 30; ++o) acc[o] = fmaf(W[o * 52 + j], x, acc[o]);
  }
  float* ob = pred + ((size_t)(b * 20 + k) * 30) * 361 + t;
#pragma unroll
  for (int o = 0; o < 30; ++o) ob[(size_t)o * 361] = acc[o] + bd[o];
}

// ---------- kernel 3b: argmax over k of cls + gather 5 box terms, write final ----------
__global__ __launch_bounds__(64) void k_sel(
    const float* __restrict__ pred, float* __restrict__ out)
{
  const int ph = blockIdx.x, a = blockIdx.y, b = blockIdx.z;
  const int p = ph * 64 + threadIdx.x;
  const bool act = p < 361;
  const int pp = act ? p : 360;
  const float* pb = pred + (size_t)b * 20 * 30 * 361 + pp;

  float best = -3.4e38f; int bidx = 0;
  float cls[20];
#pragma unroll
  for (int kk = 0; kk < 20; ++kk) {
    float s = pb[(size_t)(kk * 30 + a * 6 + 5) * 361];
    cls[kk] = s;
    if (s > best) { best = s; bidx = kk; }   // strict > keeps first index (np tie-break)
  }
  if (!act) return;
#pragma unroll
  for (int kk = 0; kk < 20; ++kk)
    out[((size_t)(b * 125 + a * 25 + 5 + kk)) * 361 + p] = cls[kk];
#pragma unroll
  for (int j = 0; j < 5; ++j)
    out[((size_t)(b * 125 + a * 25 + j)) * 361 + p]
        = pb[(size_t)(bidx * 30 + a * 6 + j) * 361];
}

extern "C" void kernel_launch(void* const* d_in, const int* in_sizes, int n_in,
                              void* d_out, int out_size, void* d_ws, size_t ws_size,
                              hipStream_t stream)
{
  const float* feat0 = (const float*)d_in[0];
  const float* feat1 = (const float*)d_in[1];
  const float* w1    = (const float*)d_in[2];
  const float* g1    = (const float*)d_in[3];
  const float* b1    = (const float*)d_in[4];
  const float* m1    = (const float*)d_in[5];
  const float* v1    = (const float*)d_in[6];
  const float* w2    = (const float*)d_in[7];
  const float* g2    = (const float*)d_in[8];
  const float* b2    = (const float*)d_in[9];
  const float* m2    = (const float*)d_in[10];
  const float* v2    = (const float*)d_in[11];
  const float* wd    = (const float*)d_in[12];
  const float* bd    = (const float*)d_in[13];
  float* out = (float*)d_out;

  char*  nbase = (char*)d_ws;
  char*  wsp   = (char*)d_ws + WSPLIT_OFF;
  float* pre   = (float*)((char*)d_ws + PRE_OFF);
  float* pred  = (float*)((char*)d_ws + WSPLIT_OFF);   // reuse wsplit region (dead after k_conv2)

  k_prep<<<dim3(5888), 256, 0, stream>>>(feat1, w1, g1, b1, m1, v1, feat0, w2, nbase, wsp);
  k_conv2<<<dim3(256), 512, 0, stream>>>(nbase, wsp, g2, b2, m2, v2, pre);
  k_pred<<<dim3(20, 16), 384, 0, stream>>>(pre, wd, bd, pred);
  k_sel<<<dim3(6, 5, 16), 64, 0, stream>>>(pred, out);
}

// Round 13
// 406.013 us; speedup vs baseline: 1.2251x; 1.0027x over previous
//
#include <hip/hip_runtime.h>
#include <hip/hip_bf16.h>

#define EPSV 1e-5f
#define SLOPEV 0.1f
#define AS1 __attribute__((address_space(1)))
#define AS3 __attribute__((address_space(3)))

typedef __attribute__((ext_vector_type(8))) _Float16 h8;  // 8 fp16 (4 VGPR) MFMA frag
typedef __attribute__((ext_vector_type(4))) float f32x4;  // MFMA acc
typedef unsigned int uint32;
typedef unsigned short ushort_t;

// ---- ws layout (bytes) ----
// A planes (fp16 split-2): plane0=H, plane1=M(x2048). Row = 1280ch x 2B = 2560B.
#define PLANE       ((size_t)18063360)
#define WSPLIT_OFF  ((size_t)36126720)    // 2 planes
// wsplit: [cc40][nt16][tap9][prec2][nj4][kq4][ln16][16B] = 47.2 MB
#define PRE_OFF     ((size_t)124968960)   // pre: 16x1024x361 f32
// pred head tensor (16x20x30x361 f32 = 13.87 MB) reuses the wsplit region after k_conv2

// conv2 LDS (bytes) -- R15/R16: BOTH A planes double-buffered in LDS + B dbuf
#define APREC  28224                 // per-prec A: 441 rows x 64B
#define ABUF   56448                 // one A buffer (2 prec)
#define BOFF   112896                // 2*ABUF
#define BBUF   24576                 // per B dbuf: 3 taps x 2 prec x 4 nj x 64 lanes x 16B
#define SMEMSZ 162048                // 2*ABUF + 2*BBUF  (<= 163840)

// fp16 2-way split of 8 f32 -> 2 x 4 packed uint32 (fp16 pairs). M term scaled x2048.
__device__ __forceinline__ void split2_pack(const float* f, uint32* ph, uint32* pm) {
#pragma unroll
  for (int i = 0; i < 4; ++i) {
    float a = f[2 * i], b = f[2 * i + 1];
    _Float16 ha = (_Float16)a, hb = (_Float16)b;          // round-to-nearest
    float ra = (a - (float)ha) * 2048.f;                  // exact residual, rescaled
    float rb = (b - (float)hb) * 2048.f;
    _Float16 ma = (_Float16)ra, mb = (_Float16)rb;
    ph[i] = (uint32)__builtin_bit_cast(ushort_t, ha) | ((uint32)__builtin_bit_cast(ushort_t, hb) << 16);
    pm[i] = (uint32)__builtin_bit_cast(ushort_t, ma) | ((uint32)__builtin_bit_cast(ushort_t, mb) << 16);
  }
}

// conv1 output store: reorg swizzle + split planes (identical math to R16)
__device__ __forceinline__ void conv1_store(char* __restrict__ nbase, const float* acc,
                                            int b, int p, int cq) {
  int y = p / 38, x = p - (p / 38) * 38;
  int q = ((y & 1) << 1) | (x & 1);
  int s = (1 + (y >> 1)) * 21 + 1 + (x >> 1);
  const int sw = (s >> 1) & 3;
  size_t rowb = ((size_t)(b * 441 + s)) * 2560;
  int grp = (q * 64 + cq * 16) >> 5;     // 64B block index in row
  char* d0 = nbase + rowb + grp * 64;
#pragma unroll
  for (int u = 0; u < 2; ++u) {
    int q4 = ((cq & 1) << 1) | u;
    uint32 H[4], M[4];
    split2_pack(&acc[u * 8], H, M);
    int off = (q4 ^ sw) << 4;
    *(uint4*)(d0 + off)         = make_uint4(H[0], H[1], H[2], H[3]);
    *(uint4*)(d0 + PLANE + off) = make_uint4(M[0], M[1], M[2], M[3]);
  }
}

// ---------- kernel 1: fused prep (R18: conv1 2px/thread merged with streaming) ----------
__global__ __launch_bounds__(256) void k_prep(
    const float* __restrict__ feat1, const float* __restrict__ w1,
    const float* __restrict__ g1, const float* __restrict__ b1,
    const float* __restrict__ m1, const float* __restrict__ v1,
    const float* __restrict__ feat0, const float* __restrict__ w2,
    char* __restrict__ nbase, char* __restrict__ wsp)
{
  __shared__ __attribute__((aligned(16))) float S[16384];  // 64KB union of all sections
  const int bid = blockIdx.x;
  const int t = threadIdx.x;

  if (bid < 192) {
    // ---- conv1: 16 img x 2 co-groups(32) x 6 px-chunks(256), 2 px/thread ----
    const int bx = bid % 6, cqq = (bid / 6) & 1, b = bid / 12;
#pragma unroll
    for (int i = 0; i < 16; ++i) {
      int f4 = t + i * 256;              // [0,4096)
      int j = f4 >> 7, c4 = (f4 & 127) * 4;
      *(float4*)&S[j * 512 + c4] = *(const float4*)&w1[(cqq * 32 + j) * 512 + c4];
    }
    __syncthreads();
    const int t2 = t & 127;
    const int cq16 = t >> 7;             // which 16-co half of the staged 32
    const int cq = cqq * 2 + cq16;       // global 16-co group 0..3
    const int pA = bx * 256 + t2;        // always < 1408 < 1444 (valid)
    const int pB = pA + 128;             // may exceed 1443 (guarded)
    const int ppB = pB < 1444 ? pB : 1443;
    const float* xpA = feat1 + (size_t)(b * 512) * 1444 + pA;
    const float* xpB = feat1 + (size_t)(b * 512) * 1444 + ppB;
    float accA[16], accB[16];
#pragma unroll
    for (int j = 0; j < 16; ++j) { accA[j] = 0.f; accB[j] = 0.f; }
#pragma unroll 2
    for (int c4 = 0; c4 < 512; c4 += 4) {
      float a0 = xpA[(size_t)(c4 + 0) * 1444];
      float a1 = xpA[(size_t)(c4 + 1) * 1444];
      float a2 = xpA[(size_t)(c4 + 2) * 1444];
      float a3 = xpA[(size_t)(c4 + 3) * 1444];
      float e0 = xpB[(size_t)(c4 + 0) * 1444];
      float e1 = xpB[(size_t)(c4 + 1) * 1444];
      float e2 = xpB[(size_t)(c4 + 2) * 1444];
      float e3 = xpB[(size_t)(c4 + 3) * 1444];
#pragma unroll
      for (int j = 0; j < 16; ++j) {
        float4 w = *(const float4*)&S[(cq16 * 16 + j) * 512 + c4];  // wave-broadcast
        accA[j] = fmaf(a0, w.x, accA[j]);
        accA[j] = fmaf(a1, w.y, accA[j]);
        accA[j] = fmaf(a2, w.z, accA[j]);
        accA[j] = fmaf(a3, w.w, accA[j]);
        accB[j] = fmaf(e0, w.x, accB[j]);
        accB[j] = fmaf(e1, w.y, accB[j]);
        accB[j] = fmaf(e2, w.z, accB[j]);
        accB[j] = fmaf(e3, w.w, accB[j]);
      }
    }
    // BN + leaky (sc/sh computed once, applied to both px)
#pragma unroll
    for (int j = 0; j < 16; ++j) {
      int co = cq * 16 + j;
      float sc = g1[co] / sqrtf(v1[co] + EPSV);
      float sh = b1[co] - m1[co] * sc;
      float va = fmaf(accA[j], sc, sh);
      accA[j] = va > 0.f ? va : SLOPEV * va;
      float vb = fmaf(accB[j], sc, sh);
      accB[j] = vb > 0.f ? vb : SLOPEV * vb;
    }
    conv1_store(nbase, accA, b, pA, cq);
    if (pB < 1444) conv1_store(nbase, accB, b, pB, cq);

  } else if (bid < 1792) {
    // ---- zero borders (2 planes) ----
    int gid = (bid - 192) * 256 + t;     // < 409600 = 160*80*32
    int c16 = gid % 160;
    int r = gid / 160;
    int bp = r % 80;
    int pi = r / 80;                     // [0,32): plane*16 + img
    int s;
    if (bp < 21) s = bp;
    else if (bp < 42) s = 399 + bp;
    else if (bp < 61) s = (bp - 41) * 21;
    else s = (bp - 60) * 21 + 20;
    int plane = pi >> 4, img = pi & 15;
    *(uint4*)(nbase + (size_t)plane * PLANE + ((size_t)(img * 441 + s)) * 2560 + c16 * 16)
        = make_uint4(0u, 0u, 0u, 0u);

  } else if (bid < 4352) {
    // ---- wsplit: w2*32 -> [cc40][nt16][tap9][prec2][nj4][kq4][ln16][16B] ----
    const int blk = bid - 1792;
    const int cc = blk >> 6, nt = (blk >> 2) & 15, nj = blk & 3;
    const float* src = w2 + ((size_t)(nt * 64 + nj * 16) * 1280 + cc * 32) * 9;
#pragma unroll
    for (int i = 0; i < 18; ++i) {
      int idx = t + i * 256;
      int col = idx / 288, d = idx - col * 288;
      S[col * 289 + d] = src[(size_t)col * 11520 + d];
    }
    __syncthreads();
#pragma unroll
    for (int it = 0; it < 3; ++it) {
      int u = t + it * 256;
      if (u < 576) {
        int tap = u / 64, kq = (u >> 4) & 3, ln = u & 15;
        float f[8];
#pragma unroll
        for (int c8 = 0; c8 < 8; ++c8) f[c8] = S[ln * 289 + (kq * 8 + c8) * 9 + tap] * 32.f;
        uint32 H[4], M[4];
        split2_pack(f, H, M);
        size_t ob = ((size_t)(cc * 16 + nt) * 9 + tap) * 8192 + nj * 1024
                  + (kq * 16 + ln) * 16;
        *(uint4*)(wsp + ob)        = make_uint4(H[0], H[1], H[2], H[3]);
        *(uint4*)(wsp + ob + 4096) = make_uint4(M[0], M[1], M[2], M[3]);
      }
    }

  } else {
    // ---- repack feat0 (ch 256-1279) -> swizzled split planes ----
    const int bid4 = bid - 4352;
    const int px = bid4 % 6, cy = (bid4 / 6) % 16, b = bid4 / 96;
    const int p0 = px * 64, c0 = 256 + cy * 64;
#pragma unroll
    for (int j = 0; j < 16; ++j) {
      int c_l = (t >> 6) + j * 4;
      int p_l = t & 63;
      float v = 0.f;
      int pos = p0 + p_l;
      if (pos < 361)
        v = feat0[((size_t)(b * 1024 + (c0 - 256) + c_l)) * 361 + pos];
      S[c_l * 65 + p_l] = v;
    }
    __syncthreads();
#pragma unroll
    for (int jj = 0; jj < 2; ++jj) {
      int p_l = (t >> 3) + jj * 32;
      int cgrp = t & 7;
      int pos = p0 + p_l;
      if (pos < 361) {
        int y = pos / 19, x = pos - (pos / 19) * 19;
        int s = (y + 1) * 21 + x + 1;
        float f[8];
#pragma unroll
        for (int u = 0; u < 8; ++u) f[u] = S[(cgrp * 8 + u) * 65 + p_l];
        uint32 H[4], M[4];
        split2_pack(f, H, M);
        int ch8 = c0 + cgrp * 8;
        int grp = ch8 >> 5, q4 = (ch8 >> 3) & 3;
        size_t byteo = ((size_t)(b * 441 + s)) * 2560 + grp * 64
                     + ((q4 ^ ((s >> 1) & 3)) << 4);
        *(uint4*)(nbase + byteo)         = make_uint4(H[0], H[1], H[2], H[3]);
        *(uint4*)(nbase + PLANE + byteo) = make_uint4(M[0], M[1], M[2], M[3]);
      }
    }
  }
}

// ---------- kernel 2: conv2 3x3 (1280->1024), 3-term split-fp16 16x16x32 MFMA ----------
// R22 = R19 verified (407.1us total, conv2 336.5us, MfmaUtil 60.8): A double-buffered
// in LDS, DMAs issued in thirds across the 3 phases, 3 __syncthreads/iter, XCD img map,
// wave-staggered tap order + cross-barrier A-frag prefetch (both neutral but verified).
// The counted-vmcnt ring rewrite (R20/R21) failed deterministically twice (identical
// absmax 0.68 under different barrier placements -> not a race; likely compiler spill
// VMEM ops polluting the hand-counted vmcnt ladder). 62% MfmaUtil is this schedule
// class's verified plateau; banking the passing optimum.
__global__ __launch_bounds__(512, 2) void k_conv2(
    const char* __restrict__ nbase, const char* __restrict__ wsp,
    const float* __restrict__ g2, const float* __restrict__ b2,
    const float* __restrict__ m2, const float* __restrict__ v2,
    float* __restrict__ pre)
{
  __shared__ __attribute__((aligned(16))) unsigned char smem[SMEMSZ];

  const int bid = blockIdx.x;
  const int img = (bid & 7) * 2 + ((bid >> 3) & 1);
  const int ntile = (bid >> 4) & 15;
  const int co0 = ntile * 64;

  const int tid = threadIdx.x;
  const int wv = tid >> 6;
  const int lane = tid & 63;
  const int ln = lane & 15;
  const int q = lane >> 4;
  const int t3base = (wv >> 2) & 1;     // stagger: waves 4-7 start at tap 1

  int arow[3];
#pragma unroll
  for (int mi = 0; mi < 3; ++mi) {
    int p = wv * 48 + mi * 16 + ln;
    p = p > 360 ? 360 : p;
    arow[mi] = (p / 19) * 21 + (p - (p / 19) * 19);
  }

  f32x4 acc0[3][4], acc1[3][4];
#pragma unroll
  for (int mi = 0; mi < 3; ++mi)
#pragma unroll
    for (int nj = 0; nj < 4; ++nj) { acc0[mi][nj] = (f32x4)0.f; acc1[mi][nj] = (f32x4)0.f; }

  const size_t imgbase = (size_t)(img * 441) * 2560;
  const size_t wnt = (size_t)ntile * 9 * 8192;

  // prologue: stage A(cc=0) into aBuf0 (3528 x 16B)
#pragma unroll
  for (int i = 0; i < 7; ++i) {
    int idx = tid + i * 512;
    if (idx < 3528) {
      int pr = idx / 1764;
      int r  = idx - pr * 1764;
      const char* src = nbase + (size_t)pr * PLANE + imgbase
                      + (size_t)(r >> 2) * 2560 + ((r & 3) << 4);
      __builtin_amdgcn_global_load_lds((const AS1 uint32*)src,
          (AS3 uint32*)(smem + idx * 16), 16, 0, 0);
    }
  }
  // prologue: B phase 0 into bBuf0 (1536 x 16B = 3/thread)
  {
    const char* bs = wsp + wnt;
#pragma unroll
    for (int i = 0; i < 3; ++i) {
      int idx = tid + i * 512;
      __builtin_amdgcn_global_load_lds((const AS1 uint32*)(bs + idx * 16),
          (AS3 uint32*)(smem + BOFF + idx * 16), 16, 0, 0);
    }
  }
  __syncthreads();   // A(0) + B(0) ready

  h8 pf0[3], pf1[3];   // cross-barrier A prefetch registers

#pragma unroll 1
  for (int cc = 0; cc < 1280; cc += 32) {
    const int cur = (cc >> 5) & 1;
    const unsigned char* aCur = smem + cur * ABUF;
    char* aNext = (char*)smem + (cur ^ 1) * ABUF;
    const int ccn = cc + 32;
    const bool pn = ccn < 1280;

#pragma unroll
    for (int p = 0; p < 3; ++p) {
      const int P = (cc >> 5) * 3 + p;
      // ---- issue B(P+1) into the other B buffer ----
      if (P + 1 < 120) {
        const int nc = (P + 1) / 3, ntb = ((P + 1) - nc * 3) * 3;
        const char* bs = wsp + ((size_t)nc * 144 + (size_t)ntb) * 8192 + wnt;
        char* bd = (char*)smem + BOFF + ((P + 1) & 1) * BBUF;
#pragma unroll
        for (int i = 0; i < 3; ++i) {
          int idx = tid + i * 512;
          __builtin_amdgcn_global_load_lds((const AS1 uint32*)(bs + idx * 16),
              (AS3 uint32*)(bd + idx * 16), 16, 0, 0);
        }
      }
      // ---- issue this phase's third of A(cc+32) into the idle A buffer ----
      if (pn) {
#pragma unroll
        for (int i = 0; i < 3; ++i) {
          int idx = p * 1176 + i * 512 + tid;
          if (idx < (p + 1) * 1176) {          // 1176 loads per phase (last i: 152 thr)
            int pr = idx / 1764;
            int r  = idx - pr * 1764;
            const char* src = nbase + (size_t)pr * PLANE + imgbase
                            + (size_t)(r >> 2) * 2560 + (ccn << 1) + ((r & 3) << 4);
            __builtin_amdgcn_global_load_lds((const AS1 uint32*)src,
                (AS3 uint32*)(aNext + idx * 16), 16, 0, 0);
          }
        }
      }

      const unsigned char* bufR = smem + BOFF + (P & 1) * BBUF;
      __builtin_amdgcn_s_setprio(1);
#pragma unroll
      for (int t3i = 0; t3i < 3; ++t3i) {
        int t3 = t3i + t3base; t3 = t3 >= 3 ? t3 - 3 : t3;   // staggered visit order
        const int trow = p * 21 + t3;
        h8 A0[3], A1[3];
        if (t3i == 0 && p > 0) {
          // consume cross-barrier prefetch (written at end of phase p-1)
#pragma unroll
          for (int mi = 0; mi < 3; ++mi) { A0[mi] = pf0[mi]; A1[mi] = pf1[mi]; }
        } else {
#pragma unroll
          for (int mi = 0; mi < 3; ++mi) {
            int srow = arow[mi] + trow;
            int aoff = srow * 64 + ((q ^ ((srow >> 1) & 3)) << 4);
            A0[mi] = *(const h8*)(aCur + aoff);           // H
            A1[mi] = *(const h8*)(aCur + APREC + aoff);   // M
          }
        }
#pragma unroll
        for (int nj = 0; nj < 4; ++nj) {
          const unsigned char* bp0 = bufR + t3 * 8192 + nj * 1024 + lane * 16;
          h8 B0 = *(const h8*)(bp0);
          h8 B1 = *(const h8*)(bp0 + 4096);
#pragma unroll
          for (int mi = 0; mi < 3; ++mi) {
            acc0[mi][nj] = __builtin_amdgcn_mfma_f32_16x16x32_f16(A0[mi], B0, acc0[mi][nj], 0, 0, 0);
            acc1[mi][nj] = __builtin_amdgcn_mfma_f32_16x16x32_f16(A0[mi], B1, acc1[mi][nj], 0, 0, 0);
            acc1[mi][nj] = __builtin_amdgcn_mfma_f32_16x16x32_f16(A1[mi], B0, acc1[mi][nj], 0, 0, 0);
          }
        }
      }
      __builtin_amdgcn_s_setprio(0);
      // ---- prefetch next phase's first-t3 A frags (aCur stable; pre-barrier) ----
      if (p < 2) {
        const int trowN = (p + 1) * 21 + t3base;
#pragma unroll
        for (int mi = 0; mi < 3; ++mi) {
          int srow = arow[mi] + trowN;
          int aoff = srow * 64 + ((q ^ ((srow >> 1) & 3)) << 4);
          pf0[mi] = *(const h8*)(aCur + aoff);
          pf1[mi] = *(const h8*)(aCur + APREC + aoff);
        }
      }
      __syncthreads();   // drains this phase's DMAs; flips B buffer (and A at p==2)
    }
  }

  // ---- epilogue: combine split terms + BN + leaky, direct stores ----
#pragma unroll
  for (int nj = 0; nj < 4; ++nj) {
    int co = co0 + nj * 16 + ln;
    float sc = g2[co] / sqrtf(v2[co] + EPSV) * 0.03125f;   // fold /32 weight scale
    float sh = b2[co] - m2[co] * (sc * 32.f);
    float* op = pre + ((size_t)(img * 1024 + co)) * 361;
#pragma unroll
    for (int mi = 0; mi < 3; ++mi) {
#pragma unroll
      for (int r = 0; r < 4; ++r) {
        int p = wv * 48 + mi * 16 + q * 4 + r;
        if (p < 361) {
          float t = fmaf(acc1[mi][nj][r], 4.8828125e-4f, acc0[mi][nj][r]);  // + acc1/2048
          float v = fmaf(t, sc, sh);
          v = v > 0.f ? v : SLOPEV * v;
          op[p] = v;
        }
      }
    }
  }
}

// ---------- kernel 3a: materialize pred[b,k,o,p] = sum_{c==k mod 20} wd[o,c]*pre[b,c,p] + bd[o] ----------
__global__ __launch_bounds__(384) void k_pred(
    const float* __restrict__ pre, const float* __restrict__ wd,
    const float* __restrict__ bd, float* __restrict__ pred)
{
  __shared__ float W[30 * 52];
  const int k = blockIdx.x;          // 0..19
  const int b = blockIdx.y;          // 0..15
  const int t = threadIdx.x;         // 0..383
  const int nj = (1023 - k) / 20 + 1;   // 52 for k<4, else 51

  for (int u = t; u < 30 * 52; u += 384) {
    int o = u / 52, j = u - o * 52;
    W[u] = (j < nj) ? wd[o * 1024 + k + 20 * j] : 0.f;
  }
  __syncthreads();
  if (t >= 361) return;

  const float* xb = pre + (size_t)b * 1024 * 361 + t;
  float acc[30];
#pragma unroll
  for (int o = 0; o < 30; ++o) acc[o] = 0.f;
  for (int j = 0; j < nj; ++j) {
    float x = xb[(size_t)(k + 20 * j) * 361];
#pragma unroll
    for (int o = 0; o < 30; ++o) acc[o] = fmaf(W[o * 52 + j], x, acc[o]);
  }
  float* ob = pred + ((size_t)(b * 20 + k) * 30) * 361 + t;
#pragma unroll
  for (int o = 0; o < 30; ++o) ob[(size_t)o * 361] = acc[o] + bd[o];
}

// ---------- kernel 3b: argmax over k of cls + gather 5 box terms, write final ----------
__global__ __launch_bounds__(64) void k_sel(
    const float* __restrict__ pred, float* __restrict__ out)
{
  const int ph = blockIdx.x, a = blockIdx.y, b = blockIdx.z;
  const int p = ph * 64 + threadIdx.x;
  const bool act = p < 361;
  const int pp = act ? p : 360;
  const float* pb = pred + (size_t)b * 20 * 30 * 361 + pp;

  float best = -3.4e38f; int bidx = 0;
  float cls[20];
#pragma unroll
  for (int kk = 0; kk < 20; ++kk) {
    float s = pb[(size_t)(kk * 30 + a * 6 + 5) * 361];
    cls[kk] = s;
    if (s > best) { best = s; bidx = kk; }   // strict > keeps first index (np tie-break)
  }
  if (!act) return;
#pragma unroll
  for (int kk = 0; kk < 20; ++kk)
    out[((size_t)(b * 125 + a * 25 + 5 + kk)) * 361 + p] = cls[kk];
#pragma unroll
  for (int j = 0; j < 5; ++j)
    out[((size_t)(b * 125 + a * 25 + j)) * 361 + p]
        = pb[(size_t)(bidx * 30 + a * 6 + j) * 361];
}

extern "C" void kernel_launch(void* const* d_in, const int* in_sizes, int n_in,
                              void* d_out, int out_size, void* d_ws, size_t ws_size,
                              hipStream_t stream)
{
  const float* feat0 = (const float*)d_in[0];
  const float* feat1 = (const float*)d_in[1];
  const float* w1    = (const float*)d_in[2];
  const float* g1    = (const float*)d_in[3];
  const float* b1    = (const float*)d_in[4];
  const float* m1    = (const float*)d_in[5];
  const float* v1    = (const float*)d_in[6];
  const float* w2    = (const float*)d_in[7];
  const float* g2    = (const float*)d_in[8];
  const float* b2    = (const float*)d_in[9];
  const float* m2    = (const float*)d_in[10];
  const float* v2    = (const float*)d_in[11];
  const float* wd    = (const float*)d_in[12];
  const float* bd    = (const float*)d_in[13];
  float* out = (float*)d_out;

  char*  nbase = (char*)d_ws;
  char*  wsp   = (char*)d_ws + WSPLIT_OFF;
  float* pre   = (float*)((char*)d_ws + PRE_OFF);
  float* pred  = (float*)((char*)d_ws + WSPLIT_OFF);   // reuse wsplit region (dead after k_conv2)

  k_prep<<<dim3(5888), 256, 0, stream>>>(feat1, w1, g1, b1, m1, v1, feat0, w2, nbase, wsp);
  k_conv2<<<dim3(256), 512, 0, stream>>>(nbase, wsp, g2, b2, m2, v2, pre);
  k_pred<<<dim3(20, 16), 384, 0, stream>>>(pre, wd, bd, pred);
  k_sel<<<dim3(6, 5, 16), 64, 0, stream>>>(pred, out);
}